// Round 8
// baseline (611.988 us; speedup 1.0000x reference)
//
#include <hip/hip_runtime.h>

#define B_    1024
#define NG_   32
#define F_    16
#define ED_   6
#define EG_   256
#define ET_   262144
#define H1_   5
#define C1_   80
#define HC1_  400
#define C2_   160
#define OBS_  512

#define S1_   408   // LDS bf16 row stride (816B: 16B-aligned, 12-bank row skew)
#define SG_   400   // global bf16 row stride
#define MSG_S 161

typedef unsigned short ushort8v __attribute__((ext_vector_type(8)));

__device__ __forceinline__ float bf2f(unsigned short u) {
  return __uint_as_float(((unsigned int)u) << 16);
}
__device__ __forceinline__ unsigned short f2bf(float f) {
  unsigned int u = __float_as_uint(f);
  u = u + 0x7FFFu + ((u >> 16) & 1u);   // RNE
  return (unsigned short)(u >> 16);
}
__device__ __forceinline__ float dot8(ushort8v hv, float4 wa, float4 wb, float acc) {
  acc = fmaf(bf2f(hv[0]), wa.x, acc);
  acc = fmaf(bf2f(hv[1]), wa.y, acc);
  acc = fmaf(bf2f(hv[2]), wa.z, acc);
  acc = fmaf(bf2f(hv[3]), wa.w, acc);
  acc = fmaf(bf2f(hv[4]), wb.x, acc);
  acc = fmaf(bf2f(hv[5]), wb.y, acc);
  acc = fmaf(bf2f(hv[6]), wb.z, acc);
  acc = fmaf(bf2f(hv[7]), wb.w, acc);
  return acc;
}

// ---------------------------------------------------------------------------
// K1: node transforms (waves 0-6) + bucket build (wave 7). One block/graph.
// ---------------------------------------------------------------------------
__global__ __launch_bounds__(512, 2)
void k1_transform_bucket(
    const float* __restrict__ x, const int* __restrict__ eidx,
    const float* __restrict__ Wl1, const float* __restrict__ bl1,
    const float* __restrict__ Wr1, const float* __restrict__ br1,
    unsigned short* __restrict__ xlg, unsigned short* __restrict__ xrg,
    int* __restrict__ eorder_g, int* __restrict__ bstart_g)
{
  __shared__ float xloc[NG_ * F_];
  __shared__ int   edst[EG_];
  const int b = blockIdx.x, tid = threadIdx.x;
  const int n0 = b * NG_, eb = b * EG_;

  if (tid < EG_) edst[tid] = eidx[ET_ + eb + tid] - n0;
  xloc[tid] = x[n0 * F_ + tid];            // NG_*F_ == 512 == blockDim
  __syncthreads();

  if (tid < 448) {
    for (int t = 0; t < 2; ++t) {
      const int ch = tid + t * 448;
      if (ch >= 800) break;
      const bool isL = (ch < 400);
      const int  c   = isL ? ch : ch - 400;
      const float* Wp = (isL ? Wl1 : Wr1) + c * F_;
      const float bias = isL ? bl1[c] : br1[c];
      unsigned short* dst = (isL ? xlg : xrg) + n0 * SG_ + c;
      float w[16];
#pragma unroll
      for (int qk = 0; qk < 4; ++qk) {
        float4 v = *(const float4*)(Wp + qk * 4);
        w[qk*4+0] = v.x; w[qk*4+1] = v.y; w[qk*4+2] = v.z; w[qk*4+3] = v.w;
      }
      for (int n = 0; n < NG_; n += 2) {
        const float* xa = &xloc[n * F_];
        float accA = bias, accB = bias;
#pragma unroll
        for (int qk = 0; qk < 4; ++qk) {
          float4 a  = *(const float4*)(xa + qk * 4);
          float4 bv = *(const float4*)(xa + F_ + qk * 4);
          accA = fmaf(a.x,  w[qk*4+0], accA); accA = fmaf(a.y,  w[qk*4+1], accA);
          accA = fmaf(a.z,  w[qk*4+2], accA); accA = fmaf(a.w,  w[qk*4+3], accA);
          accB = fmaf(bv.x, w[qk*4+0], accB); accB = fmaf(bv.y, w[qk*4+1], accB);
          accB = fmaf(bv.z, w[qk*4+2], accB); accB = fmaf(bv.w, w[qk*4+3], accB);
        }
        dst[n * SG_]       = f2bf(accA);
        dst[(n + 1) * SG_] = f2bf(accB);
      }
    }
  } else {
    const int lane = tid & 63;
    const int d    = lane & 31;
    const int half = lane >> 5;
    int cnt = 0;
    const int4* ed4 = (const int4*)edst;
    for (int i = 0; i < 32; ++i) {
      int4 v = ed4[half * 32 + i];
      cnt += (v.x == d) + (v.y == d) + (v.z == d) + (v.w == d);
    }
    const int cnt_lo = __shfl(cnt, d);
    const int total  = cnt + __shfl_xor(cnt, 32);
    int pre = total;
#pragma unroll
    for (int off = 1; off < 32; off <<= 1) {
      int tt = __shfl(pre, lane - off);
      if (d >= off) pre += tt;
    }
    const int start = pre - total;
    if (lane < 32) {
      bstart_g[b * 33 + d] = start;
      if (d == 31) bstart_g[b * 33 + 32] = pre;
    }
    int p = start + (half ? cnt_lo : 0);
    for (int i = 0; i < 32; ++i) {
      int4 v = ed4[half * 32 + i];
      const int e = half * 128 + i * 4;
      if (v.x == d) eorder_g[eb + p++] = e;
      if (v.y == d) eorder_g[eb + p++] = e + 1;
      if (v.z == d) eorder_g[eb + p++] = e + 2;
      if (v.w == d) eorder_g[eb + p++] = e + 3;
    }
  }
}

// ---------------------------------------------------------------------------
// K2: edge scores + segment softmax + aggregation. One block/graph.
// ---------------------------------------------------------------------------
__global__ __launch_bounds__(512, 2)
void k2_scores_aggregate(
    const unsigned short* __restrict__ xlg, const unsigned short* __restrict__ xrg,
    const int* __restrict__ eidx, const float* __restrict__ eattr,
    const float* __restrict__ We1, const float* __restrict__ att1,
    const float* __restrict__ bc1,
    const int* __restrict__ eorder_g, const int* __restrict__ bstart_g,
    unsigned short* __restrict__ hg)
{
  __shared__ __align__(16) unsigned short xl[NG_ * S1_];
  __shared__ __align__(16) unsigned short xr[NG_ * S1_];
  __shared__ float sc0[EG_ * H1_];
  __shared__ float sc1[EG_ * H1_];
  __shared__ float ea[EG_ * ED_];
  __shared__ int   esrc[EG_], edst[EG_], eorder[EG_];
  __shared__ int   bstart[NG_ + 1];
  __shared__ float deninv[NG_ * H1_];

  const int b = blockIdx.x, tid = threadIdx.x;
  const int n0 = b * NG_, eb = b * EG_;

  for (int i = tid; i < 3200; i += 512) {
    const bool isR = (i >= 1600);
    const int idx = isR ? i - 1600 : i;
    const int n = idx / 50, c8 = idx - n * 50;
    const ushort8v v = *(const ushort8v*)&(isR ? xrg : xlg)[(n0 + n) * SG_ + c8 * 8];
    *(ushort8v*)&(isR ? xr : xl)[n * S1_ + c8 * 8] = v;
  }
  if (tid < EG_) {
    esrc[tid]   = eidx[eb + tid] - n0;
    edst[tid]   = eidx[ET_ + eb + tid] - n0;
    eorder[tid] = eorder_g[eb + tid];
  }
  for (int i = tid; i < EG_ * ED_; i += 512) ea[i] = eattr[eb * ED_ + i];
  if (tid < NG_ + 1) bstart[tid] = bstart_g[b * 33 + tid];
  __syncthreads();

  {
    const int e = tid & 255;
    const int s = __builtin_amdgcn_readfirstlane((int)(tid >> 8) & 1);
    float* const scp = s ? sc1 : sc0;
    const int sl = esrc[e], dl = edst[e];
    const float e0 = ea[e*ED_+0], e1 = ea[e*ED_+1], e2 = ea[e*ED_+2];
    const float e3 = ea[e*ED_+3], e4 = ea[e*ED_+4], e5 = ea[e*ED_+5];
    const unsigned short* xlrow = &xl[sl * S1_ + s * 40];
    const unsigned short* xrrow = &xr[dl * S1_ + s * 40];
#pragma unroll
    for (int h = 0; h < H1_; ++h) {
      float sh = 0.f;
#pragma unroll
      for (int co = 0; co < 5; ++co) {
        const int coff  = h * C1_ + co * 8;
        const int cbase = coff + s * 40;
        ushort8v av = *(const ushort8v*)(xlrow + coff);
        ushort8v rv = *(const ushort8v*)(xrrow + coff);
#pragma unroll
        for (int u = 0; u < 8; ++u) {
          const float* wv6 = &We1[(cbase + u) * ED_];
          float t0 = fmaf(wv6[1], e1, wv6[0] * e0);
          float t1 = fmaf(wv6[3], e3, wv6[2] * e2);
          float t2 = fmaf(wv6[5], e5, wv6[4] * e4);
          float p = (bf2f(av[u]) + bf2f(rv[u])) + (t0 + (t1 + t2));
          p = fmaxf(p, 0.2f * p);
          sh = fmaf(p, att1[cbase + u], sh);
        }
      }
      scp[e * H1_ + h] = sh;
    }
  }
  __syncthreads();

  if (tid < NG_ * H1_) {
    const int d = tid & 31, h = tid >> 5;
    const int s0 = bstart[d], s1 = bstart[d + 1];
    float m = -INFINITY;
    for (int k = s0; k < s1; ++k) {
      const int e5i = eorder[k] * H1_ + h;
      m = fmaxf(m, sc0[e5i] + sc1[e5i]);
    }
    float den = 0.f;
    for (int k = s0; k < s1; ++k) {
      const int e5i = eorder[k] * H1_ + h;
      float t = expf(sc0[e5i] + sc1[e5i] - m);
      den += t;
      sc0[e5i] = t;
    }
    deninv[tid] = 1.f / (den + 1e-16f);
  }
  __syncthreads();

  for (int idx = tid; idx < NG_ * 50; idx += 512) {
    const int d  = idx / 50;
    const int co = idx - d * 50;
    const int c  = co * 8;
    const int h  = co / 10;
    const int s0 = bstart[d], s1 = bstart[d + 1];
    float acc[8] = {0.f,0.f,0.f,0.f,0.f,0.f,0.f,0.f};
    for (int k = s0; k < s1; ++k) {
      const int e = eorder[k];
      const float al = sc0[e * H1_ + h];
      ushort8v xv = *(const ushort8v*)(&xl[esrc[e] * S1_ + c]);
#pragma unroll
      for (int u = 0; u < 8; ++u) acc[u] = fmaf(al, bf2f(xv[u]), acc[u]);
    }
    const float inv = deninv[h * 32 + d];
    ushort8v hv;
#pragma unroll
    for (int u = 0; u < 8; ++u)
      hv[u] = f2bf(fmaxf(fmaf(acc[u], inv, bc1[c + u]), 0.f));
    *(ushort8v*)&hg[(n0 + d) * SG_ + c] = hv;
  }
}

// ---------------------------------------------------------------------------
// K3 (NEW): barrier-free, one WAVE per graph (1024 blocks x 64 threads).
// All coordination via __shfl; LDS pane private to the wave; h-row chunks
// hoisted to registers; 4 independent FMA chains per lane (cc-quads).
// ---------------------------------------------------------------------------
__global__ __launch_bounds__(64, 3)
void k3_wave(
    const int* __restrict__ eidx, const float* __restrict__ eattr,
    const unsigned short* __restrict__ hg,
    const float* __restrict__ Wl2, const float* __restrict__ bl2,
    const float* __restrict__ Wr2, const float* __restrict__ br2,
    const float* __restrict__ We2, const float* __restrict__ att2,
    const float* __restrict__ bc2,
    const int* __restrict__ eorder_g, const int* __restrict__ bstart_g,
    float* __restrict__ egoH)
{
  __shared__ __align__(16) unsigned short hrows[9 * S1_];  // rows 0..7 slots; 8 ego
  __shared__ float msg[8 * MSG_S];
  __shared__ float xr2v[C2_];

  const int b  = blockIdx.x;
  const int ln = threadIdx.x;
  const int qq = ln >> 3;          // k-part 0..7
  const int jv = ln & 7;           // slot / cc-group 0..7
  const int n0 = b * NG_, eb = b * EG_;

  const int nE = bstart_g[b * 33 + 1];

  // stage ego row into row 8 (wave-synchronous)
  if (ln < 50)
    *(ushort8v*)&hrows[8 * S1_ + ln * 8] =
        *(const ushort8v*)&hg[(size_t)n0 * SG_ + ln * 8];

  // ego h chunks -> registers
  ushort8v ec[7];
#pragma unroll
  for (int i = 0; i < 6; ++i)
    ec[i] = *(const ushort8v*)&hrows[8 * S1_ + qq * 8 + i * 64];
  ec[6] = *(const ushort8v*)&hrows[8 * S1_ + ((qq < 2) ? 384 + qq * 8 : 0)];

  // xr2v = Wr2 @ h_ego + br2 ; lane covers cc = p*32 + jv*4 + {0..3}
  for (int p = 0; p < 5; ++p) {
    const int cc0 = p * 32 + jv * 4;
    const float* w0 = &Wr2[(size_t)cc0 * HC1_];
    const float* w1 = w0 + HC1_;
    const float* w2 = w1 + HC1_;
    const float* w3 = w2 + HC1_;
    float a0 = 0.f, a1 = 0.f, a2 = 0.f, a3 = 0.f;
#pragma unroll
    for (int i = 0; i < 6; ++i) {
      const int k = qq * 8 + i * 64;
      a0 = dot8(ec[i], *(const float4*)(w0+k), *(const float4*)(w0+k+4), a0);
      a1 = dot8(ec[i], *(const float4*)(w1+k), *(const float4*)(w1+k+4), a1);
      a2 = dot8(ec[i], *(const float4*)(w2+k), *(const float4*)(w2+k+4), a2);
      a3 = dot8(ec[i], *(const float4*)(w3+k), *(const float4*)(w3+k+4), a3);
    }
    if (qq < 2) {
      const int k = 384 + qq * 8;
      a0 = dot8(ec[6], *(const float4*)(w0+k), *(const float4*)(w0+k+4), a0);
      a1 = dot8(ec[6], *(const float4*)(w1+k), *(const float4*)(w1+k+4), a1);
      a2 = dot8(ec[6], *(const float4*)(w2+k), *(const float4*)(w2+k+4), a2);
      a3 = dot8(ec[6], *(const float4*)(w3+k), *(const float4*)(w3+k+4), a3);
    }
    a0 += __shfl_xor(a0, 8); a0 += __shfl_xor(a0, 16); a0 += __shfl_xor(a0, 32);
    a1 += __shfl_xor(a1, 8); a1 += __shfl_xor(a1, 16); a1 += __shfl_xor(a1, 32);
    a2 += __shfl_xor(a2, 8); a2 += __shfl_xor(a2, 16); a2 += __shfl_xor(a2, 32);
    a3 += __shfl_xor(a3, 8); a3 += __shfl_xor(a3, 16); a3 += __shfl_xor(a3, 32);
    if (qq == 0) {
      xr2v[cc0 + 0] = a0 + br2[cc0 + 0];
      xr2v[cc0 + 1] = a1 + br2[cc0 + 1];
      xr2v[cc0 + 2] = a2 + br2[cc0 + 2];
      xr2v[cc0 + 3] = a3 + br2[cc0 + 3];
    }
  }

  float oAcc0 = 0.f, oAcc1 = 0.f, oAcc2 = 0.f;
  float m_run = -INFINITY, d_run = 0.f;

  for (int c0 = 0; c0 < nE; c0 += 8) {
    const int nc = min(8, nE - c0);

    // slot meta in lane registers (lane j holds slot j)
    int src = 0;
    float ea0=0.f, ea1=0.f, ea2=0.f, ea3=0.f, ea4=0.f, ea5=0.f;
    if (ln < nc) {
      const int e = eorder_g[eb + c0 + ln];
      src = eidx[eb + e] - n0;
      const float* ap = &eattr[(size_t)(eb + e) * ED_];
      ea0 = ap[0]; ea1 = ap[1]; ea2 = ap[2];
      ea3 = ap[3]; ea4 = ap[4]; ea5 = ap[5];
    }
    // stage src rows (wave-synchronous)
#pragma unroll
    for (int r = 0; r < 8; ++r) {
      if (r < nc) {
        const int sr = __shfl(src, r);
        if (ln < 50)
          *(ushort8v*)&hrows[r * S1_ + ln * 8] =
              *(const ushort8v*)&hg[(size_t)(n0 + sr) * SG_ + ln * 8];
      }
    }
    // slot h chunks -> registers (slot = jv)
    ushort8v hc[7];
#pragma unroll
    for (int i = 0; i < 6; ++i)
      hc[i] = *(const ushort8v*)&hrows[jv * S1_ + qq * 8 + i * 64];
    hc[6] = *(const ushort8v*)&hrows[jv * S1_ + ((qq < 2) ? 384 + qq * 8 : 0)];

    // messages: msg[jv][cc] = Wl2[cc] . h_src[jv] + bl2 ; 4 cc per p
    for (int p = 0; p < 40; ++p) {
      const int cc0 = p * 4;
      const float* w0 = &Wl2[(size_t)cc0 * HC1_];
      const float* w1 = w0 + HC1_;
      const float* w2 = w1 + HC1_;
      const float* w3 = w2 + HC1_;
      float a0 = 0.f, a1 = 0.f, a2 = 0.f, a3 = 0.f;
#pragma unroll
      for (int i = 0; i < 6; ++i) {
        const int k = qq * 8 + i * 64;
        a0 = dot8(hc[i], *(const float4*)(w0+k), *(const float4*)(w0+k+4), a0);
        a1 = dot8(hc[i], *(const float4*)(w1+k), *(const float4*)(w1+k+4), a1);
        a2 = dot8(hc[i], *(const float4*)(w2+k), *(const float4*)(w2+k+4), a2);
        a3 = dot8(hc[i], *(const float4*)(w3+k), *(const float4*)(w3+k+4), a3);
      }
      if (qq < 2) {
        const int k = 384 + qq * 8;
        a0 = dot8(hc[6], *(const float4*)(w0+k), *(const float4*)(w0+k+4), a0);
        a1 = dot8(hc[6], *(const float4*)(w1+k), *(const float4*)(w1+k+4), a1);
        a2 = dot8(hc[6], *(const float4*)(w2+k), *(const float4*)(w2+k+4), a2);
        a3 = dot8(hc[6], *(const float4*)(w3+k), *(const float4*)(w3+k+4), a3);
      }
      a0 += __shfl_xor(a0, 8); a0 += __shfl_xor(a0, 16); a0 += __shfl_xor(a0, 32);
      a1 += __shfl_xor(a1, 8); a1 += __shfl_xor(a1, 16); a1 += __shfl_xor(a1, 32);
      a2 += __shfl_xor(a2, 8); a2 += __shfl_xor(a2, 16); a2 += __shfl_xor(a2, 32);
      a3 += __shfl_xor(a3, 8); a3 += __shfl_xor(a3, 16); a3 += __shfl_xor(a3, 32);
      if (qq == 0 && jv < nc) {
        msg[jv * MSG_S + cc0 + 0] = a0 + bl2[cc0 + 0];
        msg[jv * MSG_S + cc0 + 1] = a1 + bl2[cc0 + 1];
        msg[jv * MSG_S + cc0 + 2] = a2 + bl2[cc0 + 2];
        msg[jv * MSG_S + cc0 + 3] = a3 + bl2[cc0 + 3];
      }
    }

    // scores: 8 lanes per slot (s = ln>>3, q8 = ln&7)
    const int s  = ln >> 3;
    const int q8 = ln & 7;
    const float f0 = __shfl(ea0, s), f1 = __shfl(ea1, s), f2 = __shfl(ea2, s);
    const float f3 = __shfl(ea3, s), f4 = __shfl(ea4, s), f5 = __shfl(ea5, s);
    float sv = 0.f;
    if (s < nc) {
      for (int i = 0; i < 20; ++i) {
        const int c2 = q8 * 20 + i;
        const float* wv6 = &We2[c2 * ED_];
        float t0 = fmaf(wv6[1], f1, wv6[0] * f0);
        float t1 = fmaf(wv6[3], f3, wv6[2] * f2);
        float t2 = fmaf(wv6[5], f5, wv6[4] * f4);
        float pp = msg[s * MSG_S + c2] + xr2v[c2] + (t0 + (t1 + t2));
        pp = fmaxf(pp, 0.2f * pp);
        sv = fmaf(pp, att2[c2], sv);
      }
    }
    sv += __shfl_xor(sv, 1); sv += __shfl_xor(sv, 2); sv += __shfl_xor(sv, 4);

    // online softmax (replicated in all lanes) + accumulate
    float scj[8], wj[8];
    float mg = m_run;
#pragma unroll
    for (int j = 0; j < 8; ++j) {
      scj[j] = __shfl(sv, j * 8);
      if (j < nc) mg = fmaxf(mg, scj[j]);
    }
    const float scl = expf(m_run - mg);     // 0 on first chunk
    float wsum = 0.f;
#pragma unroll
    for (int j = 0; j < 8; ++j) {
      wj[j] = (j < nc) ? expf(scj[j] - mg) : 0.f;
      wsum += wj[j];
    }
    d_run = d_run * scl + wsum;
    m_run = mg;

    {
      float o0 = oAcc0 * scl, o1 = oAcc1 * scl, o2 = oAcc2 * scl;
      const int ccA = ln, ccB = ln + 64, ccC = ln + 128;
#pragma unroll
      for (int j = 0; j < 8; ++j) {
        const float* mrow = &msg[j * MSG_S];
        const float mA = (j < nc) ? mrow[ccA] : 0.f;
        const float mB = (j < nc) ? mrow[ccB] : 0.f;
        const float mC = (j < nc && ccC < C2_) ? mrow[ccC] : 0.f;
        o0 = fmaf(wj[j], mA, o0);
        o1 = fmaf(wj[j], mB, o1);
        o2 = fmaf(wj[j], mC, o2);
      }
      oAcc0 = o0; oAcc1 = o1; oAcc2 = o2;
    }
  }

  // finalize: out = relu(o/den + bc2)
  {
    const float inv = 1.f / (d_run + 1e-16f);
    const int ccA = ln, ccB = ln + 64, ccC = ln + 128;
    egoH[b * C2_ + ccA] = fmaxf(fmaf(oAcc0, inv, bc2[ccA]), 0.f);
    egoH[b * C2_ + ccB] = fmaxf(fmaf(oAcc1, inv, bc2[ccB]), 0.f);
    if (ccC < C2_)
      egoH[b * C2_ + ccC] = fmaxf(fmaf(oAcc2, inv, bc2[ccC]), 0.f);
  }
}

// ---------------------------------------------------------------------------
// K4: dense head + MLP (unchanged). 256 blocks x 512 threads.
// ---------------------------------------------------------------------------
__global__ __launch_bounds__(512, 2)
void mlp_head_kernel(
    const float* __restrict__ egoH,
    const float* __restrict__ Wd1, const float* __restrict__ bd1,
    const float* __restrict__ Wd2, const float* __restrict__ bd2,
    const float* __restrict__ Wf1, const float* __restrict__ bf1,
    const float* __restrict__ Wf2, const float* __restrict__ bf2,
    const float* __restrict__ Wm,  const float* __restrict__ bm,
    const float* __restrict__ Ws,  const float* __restrict__ bs,
    float* __restrict__ out)
{
  __shared__ float hE[4 * C2_];
  __shared__ float t1[4 * NG_];
  __shared__ float dbuf[4 * OBS_];
  __shared__ float f1b[4 * 256];
  __shared__ float f2b[4 * 256];

  const int g0  = blockIdx.x * 4;
  const int tid = threadIdx.x;

  for (int i = tid; i < 4 * C2_; i += 512) hE[i] = egoH[g0 * C2_ + i];
  __syncthreads();

  if (tid < 4 * NG_) {
    const int g = tid >> 5, o = tid & 31;
    float acc = bd1[o];
    const float* w  = &Wd1[o * C2_];
    const float* hp = &hE[g * C2_];
    for (int k = 0; k < C2_; k += 4) {
      float4 hv = *(const float4*)(hp + k);
      float4 wv = *(const float4*)(w + k);
      acc = fmaf(hv.x, wv.x, acc); acc = fmaf(hv.y, wv.y, acc);
      acc = fmaf(hv.z, wv.z, acc); acc = fmaf(hv.w, wv.w, acc);
    }
    t1[tid] = acc;
  }
  __syncthreads();

  for (int idx = tid; idx < 4 * OBS_; idx += 512) {
    const int g = idx >> 9, o = idx & 511;
    float acc = bd2[o];
    const float* w  = &Wd2[o * NG_];
    const float* tp = &t1[g * NG_];
#pragma unroll
    for (int k = 0; k < NG_; k += 4) {
      float4 tv = *(const float4*)(tp + k);
      float4 wv = *(const float4*)(w + k);
      acc = fmaf(tv.x, wv.x, acc); acc = fmaf(tv.y, wv.y, acc);
      acc = fmaf(tv.z, wv.z, acc); acc = fmaf(tv.w, wv.w, acc);
    }
    dbuf[idx] = tanhf(acc);
  }
  __syncthreads();

  {
    const int o = tid & 255, gg = tid >> 8;
    const float* w  = &Wf1[o * OBS_];
    const float* dA = &dbuf[(gg * 2 + 0) * OBS_];
    const float* dB = &dbuf[(gg * 2 + 1) * OBS_];
    float a0 = bf1[o], a1 = a0;
#pragma unroll 2
    for (int k = 0; k < OBS_; k += 4) {
      float4 wv = *(const float4*)(w + k);
      float4 xA = *(const float4*)(dA + k);
      float4 xB = *(const float4*)(dB + k);
      a0 = fmaf(xA.x, wv.x, a0); a0 = fmaf(xA.y, wv.y, a0);
      a0 = fmaf(xA.z, wv.z, a0); a0 = fmaf(xA.w, wv.w, a0);
      a1 = fmaf(xB.x, wv.x, a1); a1 = fmaf(xB.y, wv.y, a1);
      a1 = fmaf(xB.z, wv.z, a1); a1 = fmaf(xB.w, wv.w, a1);
    }
    f1b[(gg * 2 + 0) * 256 + o] = fmaxf(a0, 0.f);
    f1b[(gg * 2 + 1) * 256 + o] = fmaxf(a1, 0.f);
  }
  __syncthreads();

  {
    const int o = tid & 255, gg = tid >> 8;
    const float* w  = &Wf2[o * 256];
    const float* dA = &f1b[(gg * 2 + 0) * 256];
    const float* dB = &f1b[(gg * 2 + 1) * 256];
    float a0 = bf2[o], a1 = a0;
#pragma unroll 2
    for (int k = 0; k < 256; k += 4) {
      float4 wv = *(const float4*)(w + k);
      float4 xA = *(const float4*)(dA + k);
      float4 xB = *(const float4*)(dB + k);
      a0 = fmaf(xA.x, wv.x, a0); a0 = fmaf(xA.y, wv.y, a0);
      a0 = fmaf(xA.z, wv.z, a0); a0 = fmaf(xA.w, wv.w, a0);
      a1 = fmaf(xB.x, wv.x, a1); a1 = fmaf(xB.y, wv.y, a1);
      a1 = fmaf(xB.z, wv.z, a1); a1 = fmaf(xB.w, wv.w, a1);
    }
    f2b[(gg * 2 + 0) * 256 + o] = fmaxf(a0, 0.f);
    f2b[(gg * 2 + 1) * 256 + o] = fmaxf(a1, 0.f);
  }
  __syncthreads();

  if (tid < 16) {
    const int g  = tid >> 2;
    const int a  = (tid >> 1) & 1;
    const int hm = tid & 1;
    const float* fp = &f2b[g * 256];
    const float* w  = hm ? &Ws[a * 256] : &Wm[a * 256];
    float acc = hm ? bs[a] : bm[a];
    for (int k = 0; k < 256; ++k) acc = fmaf(fp[k], w[k], acc);
    if (hm == 0) out[(g0 + g) * 2 + a] = acc;
    else         out[2048 + (g0 + g) * 2 + a] = -5.0f + 3.5f * (tanhf(acc) + 1.0f);
  }
}

extern "C" void kernel_launch(void* const* d_in, const int* in_sizes, int n_in,
                              void* d_out, int out_size, void* d_ws, size_t ws_size,
                              hipStream_t stream) {
  const float* x     = (const float*)d_in[0];
  const int*   eidx  = (const int*)d_in[1];
  const float* eattr = (const float*)d_in[2];
  const float* Wl1 = (const float*)d_in[3];  const float* bl1 = (const float*)d_in[4];
  const float* Wr1 = (const float*)d_in[5];  const float* br1 = (const float*)d_in[6];
  const float* We1 = (const float*)d_in[7];  const float* att1= (const float*)d_in[8];
  const float* bc1 = (const float*)d_in[9];
  const float* Wl2 = (const float*)d_in[10]; const float* bl2 = (const float*)d_in[11];
  const float* Wr2 = (const float*)d_in[12]; const float* br2 = (const float*)d_in[13];
  const float* We2 = (const float*)d_in[14]; const float* att2= (const float*)d_in[15];
  const float* bc2 = (const float*)d_in[16];
  const float* Wd1 = (const float*)d_in[17]; const float* bd1 = (const float*)d_in[18];
  const float* Wd2 = (const float*)d_in[19]; const float* bd2 = (const float*)d_in[20];
  const float* Wf1 = (const float*)d_in[21]; const float* bf1 = (const float*)d_in[22];
  const float* Wf2 = (const float*)d_in[23]; const float* bf2 = (const float*)d_in[24];
  const float* Wm  = (const float*)d_in[25]; const float* bm  = (const float*)d_in[26];
  const float* Ws  = (const float*)d_in[27]; const float* bs  = (const float*)d_in[28];

  // workspace layout (~54.3 MB)
  unsigned short* xlg = (unsigned short*)d_ws;          // [32768][400] bf16 = 26.2 MB
  unsigned short* hg  = xlg + 32768 * SG_;              // xr, then h     = 26.2 MB
  int* eorder_g = (int*)(hg + 32768 * SG_);             // 1.05 MB
  int* bstart_g = eorder_g + ET_;                       // 132 KB
  float* egoH   = (float*)(bstart_g + B_ * 33);         // 640 KB

  k1_transform_bucket<<<B_, 512, 0, stream>>>(
      x, eidx, Wl1, bl1, Wr1, br1, xlg, hg, eorder_g, bstart_g);

  k2_scores_aggregate<<<B_, 512, 0, stream>>>(
      xlg, hg, eidx, eattr, We1, att1, bc1, eorder_g, bstart_g, hg);

  k3_wave<<<B_, 64, 0, stream>>>(
      eidx, eattr, hg, Wl2, bl2, Wr2, br2, We2, att2, bc2,
      eorder_g, bstart_g, egoH);

  mlp_head_kernel<<<B_ / 4, 512, 0, stream>>>(
      egoH, Wd1, bd1, Wd2, bd2, Wf1, bf1, Wf2, bf2, Wm, bm, Ws, bs,
      (float*)d_out);
}

// Round 9
// 319.351 us; speedup vs baseline: 1.9163x; 1.9163x over previous
//
#include <hip/hip_runtime.h>

#define B_    1024
#define NG_   32
#define F_    16
#define ED_   6
#define EG_   256
#define ET_   262144
#define H1_   5
#define C1_   80
#define HC1_  400
#define C2_   160
#define OBS_  512

#define S1_   408   // LDS bf16 row stride (816B: 16B-aligned, 2-way-max bank alias)
#define SG_   400   // global bf16 row stride
#define CAP_  40960 // packed ego-edge capacity (mean total ~8192, 89-sigma margin)

typedef unsigned short ushort8v __attribute__((ext_vector_type(8)));

__device__ __forceinline__ float bf2f(unsigned short u) {
  return __uint_as_float(((unsigned int)u) << 16);
}
__device__ __forceinline__ unsigned short f2bf(float f) {
  unsigned int u = __float_as_uint(f);
  u = u + 0x7FFFu + ((u >> 16) & 1u);   // RNE
  return (unsigned short)(u >> 16);
}
__device__ __forceinline__ float dot8(ushort8v hv, float4 wa, float4 wb, float acc) {
  acc = fmaf(bf2f(hv[0]), wa.x, acc);
  acc = fmaf(bf2f(hv[1]), wa.y, acc);
  acc = fmaf(bf2f(hv[2]), wa.z, acc);
  acc = fmaf(bf2f(hv[3]), wa.w, acc);
  acc = fmaf(bf2f(hv[4]), wb.x, acc);
  acc = fmaf(bf2f(hv[5]), wb.y, acc);
  acc = fmaf(bf2f(hv[6]), wb.z, acc);
  acc = fmaf(bf2f(hv[7]), wb.w, acc);
  return acc;
}

// ---------------------------------------------------------------------------
// K1: node transforms (waves 0-6) + bucket build (wave 7). One block/graph.
// ---------------------------------------------------------------------------
__global__ __launch_bounds__(512, 2)
void k1_transform_bucket(
    const float* __restrict__ x, const int* __restrict__ eidx,
    const float* __restrict__ Wl1, const float* __restrict__ bl1,
    const float* __restrict__ Wr1, const float* __restrict__ br1,
    unsigned short* __restrict__ xlg, unsigned short* __restrict__ xrg,
    int* __restrict__ eorder_g, int* __restrict__ bstart_g)
{
  __shared__ float xloc[NG_ * F_];
  __shared__ int   edst[EG_];
  const int b = blockIdx.x, tid = threadIdx.x;
  const int n0 = b * NG_, eb = b * EG_;

  if (tid < EG_) edst[tid] = eidx[ET_ + eb + tid] - n0;
  xloc[tid] = x[n0 * F_ + tid];            // NG_*F_ == 512 == blockDim
  __syncthreads();

  if (tid < 448) {
    for (int t = 0; t < 2; ++t) {
      const int ch = tid + t * 448;
      if (ch >= 800) break;
      const bool isL = (ch < 400);
      const int  c   = isL ? ch : ch - 400;
      const float* Wp = (isL ? Wl1 : Wr1) + c * F_;
      const float bias = isL ? bl1[c] : br1[c];
      unsigned short* dst = (isL ? xlg : xrg) + n0 * SG_ + c;
      float w[16];
#pragma unroll
      for (int qk = 0; qk < 4; ++qk) {
        float4 v = *(const float4*)(Wp + qk * 4);
        w[qk*4+0] = v.x; w[qk*4+1] = v.y; w[qk*4+2] = v.z; w[qk*4+3] = v.w;
      }
      for (int n = 0; n < NG_; n += 2) {
        const float* xa = &xloc[n * F_];
        float accA = bias, accB = bias;
#pragma unroll
        for (int qk = 0; qk < 4; ++qk) {
          float4 a  = *(const float4*)(xa + qk * 4);
          float4 bv = *(const float4*)(xa + F_ + qk * 4);
          accA = fmaf(a.x,  w[qk*4+0], accA); accA = fmaf(a.y,  w[qk*4+1], accA);
          accA = fmaf(a.z,  w[qk*4+2], accA); accA = fmaf(a.w,  w[qk*4+3], accA);
          accB = fmaf(bv.x, w[qk*4+0], accB); accB = fmaf(bv.y, w[qk*4+1], accB);
          accB = fmaf(bv.z, w[qk*4+2], accB); accB = fmaf(bv.w, w[qk*4+3], accB);
        }
        dst[n * SG_]       = f2bf(accA);
        dst[(n + 1) * SG_] = f2bf(accB);
      }
    }
  } else {
    const int lane = tid & 63;
    const int d    = lane & 31;
    const int half = lane >> 5;
    int cnt = 0;
    const int4* ed4 = (const int4*)edst;
    for (int i = 0; i < 32; ++i) {
      int4 v = ed4[half * 32 + i];
      cnt += (v.x == d) + (v.y == d) + (v.z == d) + (v.w == d);
    }
    const int cnt_lo = __shfl(cnt, d);
    const int total  = cnt + __shfl_xor(cnt, 32);
    int pre = total;
#pragma unroll
    for (int off = 1; off < 32; off <<= 1) {
      int tt = __shfl(pre, lane - off);
      if (d >= off) pre += tt;
    }
    const int start = pre - total;
    if (lane < 32) {
      bstart_g[b * 33 + d] = start;
      if (d == 31) bstart_g[b * 33 + 32] = pre;
    }
    int p = start + (half ? cnt_lo : 0);
    for (int i = 0; i < 32; ++i) {
      int4 v = ed4[half * 32 + i];
      const int e = half * 128 + i * 4;
      if (v.x == d) eorder_g[eb + p++] = e;
      if (v.y == d) eorder_g[eb + p++] = e + 1;
      if (v.z == d) eorder_g[eb + p++] = e + 2;
      if (v.w == d) eorder_g[eb + p++] = e + 3;
    }
  }
}

// ---------------------------------------------------------------------------
// K0b: scan nE over graphs -> egoOff; emit packed meta (src node, edge id).
// Single block, 1024 threads (thread = graph).
// ---------------------------------------------------------------------------
__global__ __launch_bounds__(1024, 1)
void k0b_pack(const int* __restrict__ bstart_g, const int* __restrict__ eorder_g,
              const int* __restrict__ eidx,
              int* __restrict__ egoOff, int* __restrict__ meta_node,
              int* __restrict__ meta_eid)
{
  __shared__ int scanBuf[B_];
  const int b = threadIdx.x;
  const int nE = bstart_g[b * 33 + 1];
  scanBuf[b] = nE;
  __syncthreads();
  for (int off = 1; off < B_; off <<= 1) {
    int v = (b >= off) ? scanBuf[b - off] : 0;
    __syncthreads();
    scanBuf[b] += v;
    __syncthreads();
  }
  const int start = scanBuf[b] - nE;
  egoOff[b] = start;
  if (b == B_ - 1) egoOff[B_] = scanBuf[b];
  if (start + nE <= CAP_) {
    for (int j = 0; j < nE; ++j) {
      const int e = eorder_g[b * EG_ + j];
      meta_node[start + j] = eidx[b * EG_ + e];   // global src node id
      meta_eid[start + j]  = b * EG_ + e;         // global edge id
    }
  }
}

// ---------------------------------------------------------------------------
// K2: edge scores + segment softmax + aggregation. One block/graph.
// ---------------------------------------------------------------------------
__global__ __launch_bounds__(512, 2)
void k2_scores_aggregate(
    const unsigned short* __restrict__ xlg, const unsigned short* __restrict__ xrg,
    const int* __restrict__ eidx, const float* __restrict__ eattr,
    const float* __restrict__ We1, const float* __restrict__ att1,
    const float* __restrict__ bc1,
    const int* __restrict__ eorder_g, const int* __restrict__ bstart_g,
    unsigned short* __restrict__ hg)
{
  __shared__ __align__(16) unsigned short xl[NG_ * S1_];
  __shared__ __align__(16) unsigned short xr[NG_ * S1_];
  __shared__ float sc0[EG_ * H1_];
  __shared__ float sc1[EG_ * H1_];
  __shared__ float ea[EG_ * ED_];
  __shared__ int   esrc[EG_], edst[EG_], eorder[EG_];
  __shared__ int   bstart[NG_ + 1];
  __shared__ float deninv[NG_ * H1_];

  const int b = blockIdx.x, tid = threadIdx.x;
  const int n0 = b * NG_, eb = b * EG_;

  for (int i = tid; i < 3200; i += 512) {
    const bool isR = (i >= 1600);
    const int idx = isR ? i - 1600 : i;
    const int n = idx / 50, c8 = idx - n * 50;
    const ushort8v v = *(const ushort8v*)&(isR ? xrg : xlg)[(n0 + n) * SG_ + c8 * 8];
    *(ushort8v*)&(isR ? xr : xl)[n * S1_ + c8 * 8] = v;
  }
  if (tid < EG_) {
    esrc[tid]   = eidx[eb + tid] - n0;
    edst[tid]   = eidx[ET_ + eb + tid] - n0;
    eorder[tid] = eorder_g[eb + tid];
  }
  for (int i = tid; i < EG_ * ED_; i += 512) ea[i] = eattr[eb * ED_ + i];
  if (tid < NG_ + 1) bstart[tid] = bstart_g[b * 33 + tid];
  __syncthreads();

  {
    const int e = tid & 255;
    const int s = __builtin_amdgcn_readfirstlane((int)(tid >> 8) & 1);
    float* const scp = s ? sc1 : sc0;
    const int sl = esrc[e], dl = edst[e];
    const float e0 = ea[e*ED_+0], e1 = ea[e*ED_+1], e2 = ea[e*ED_+2];
    const float e3 = ea[e*ED_+3], e4 = ea[e*ED_+4], e5 = ea[e*ED_+5];
    const unsigned short* xlrow = &xl[sl * S1_ + s * 40];
    const unsigned short* xrrow = &xr[dl * S1_ + s * 40];
#pragma unroll
    for (int h = 0; h < H1_; ++h) {
      float sh = 0.f;
#pragma unroll
      for (int co = 0; co < 5; ++co) {
        const int coff  = h * C1_ + co * 8;
        const int cbase = coff + s * 40;
        ushort8v av = *(const ushort8v*)(xlrow + coff);
        ushort8v rv = *(const ushort8v*)(xrrow + coff);
#pragma unroll
        for (int u = 0; u < 8; ++u) {
          const float* wv6 = &We1[(cbase + u) * ED_];
          float t0 = fmaf(wv6[1], e1, wv6[0] * e0);
          float t1 = fmaf(wv6[3], e3, wv6[2] * e2);
          float t2 = fmaf(wv6[5], e5, wv6[4] * e4);
          float p = (bf2f(av[u]) + bf2f(rv[u])) + (t0 + (t1 + t2));
          p = fmaxf(p, 0.2f * p);
          sh = fmaf(p, att1[cbase + u], sh);
        }
      }
      scp[e * H1_ + h] = sh;
    }
  }
  __syncthreads();

  if (tid < NG_ * H1_) {
    const int d = tid & 31, h = tid >> 5;
    const int s0 = bstart[d], s1 = bstart[d + 1];
    float m = -INFINITY;
    for (int k = s0; k < s1; ++k) {
      const int e5i = eorder[k] * H1_ + h;
      m = fmaxf(m, sc0[e5i] + sc1[e5i]);
    }
    float den = 0.f;
    for (int k = s0; k < s1; ++k) {
      const int e5i = eorder[k] * H1_ + h;
      float t = expf(sc0[e5i] + sc1[e5i] - m);
      den += t;
      sc0[e5i] = t;
    }
    deninv[tid] = 1.f / (den + 1e-16f);
  }
  __syncthreads();

  for (int idx = tid; idx < NG_ * 50; idx += 512) {
    const int d  = idx / 50;
    const int co = idx - d * 50;
    const int c  = co * 8;
    const int h  = co / 10;
    const int s0 = bstart[d], s1 = bstart[d + 1];
    float acc[8] = {0.f,0.f,0.f,0.f,0.f,0.f,0.f,0.f};
    for (int k = s0; k < s1; ++k) {
      const int e = eorder[k];
      const float al = sc0[e * H1_ + h];
      ushort8v xv = *(const ushort8v*)(&xl[esrc[e] * S1_ + c]);
#pragma unroll
      for (int u = 0; u < 8; ++u) acc[u] = fmaf(al, bf2f(xv[u]), acc[u]);
    }
    const float inv = deninv[h * 32 + d];
    ushort8v hv;
#pragma unroll
    for (int u = 0; u < 8; ++u)
      hv[u] = f2bf(fmaxf(fmaf(acc[u], inv, bc1[c + u]), 0.f));
    *(ushort8v*)&hg[(n0 + d) * SG_ + c] = hv;
  }
}

// ---------------------------------------------------------------------------
// K3a: packed GEMM. Blocks 0..15: xr2v = egoH_rows @ Wr2^T (+br2), 64 rows
// each. Blocks 16..: grid-stride over packed ego-edge rows, msg = rows @
// Wl2^T (+bl2). 64 rows staged in LDS per chunk; thread=(edge-slot, cc-grp):
// 4 rows x 5 cc accumulators; one weight load feeds 4 FMA chains.
// ---------------------------------------------------------------------------
__global__ __launch_bounds__(512, 2)
void k3a_gemm(const unsigned short* __restrict__ hg,
              const int* __restrict__ meta_node, const int* __restrict__ egoOff,
              const float* __restrict__ Wl2, const float* __restrict__ bl2,
              const float* __restrict__ Wr2, const float* __restrict__ br2,
              float* __restrict__ msgP, float* __restrict__ xr2v_g)
{
  __shared__ __align__(16) unsigned short rows[64 * S1_];
  __shared__ int rnode[64];
  __shared__ int sTot;
  const int tid = threadIdx.x;
  const bool isX = (blockIdx.x < 16);
  if (tid == 0) sTot = egoOff[B_];
  __syncthreads();
  const int total = sTot;

  const float* W    = isX ? Wr2 : Wl2;
  const float* bias = isX ? br2 : bl2;
  float* outB       = isX ? xr2v_g : msgP;

  const int es = tid & 15;      // edge slot 0..15 (rows es, es+16, es+32, es+48)
  const int cg = tid >> 4;      // cc group 0..31 -> cc = cg*5 + {0..4}
  const float* wp[5];
#pragma unroll
  for (int i = 0; i < 5; ++i) wp[i] = &W[(size_t)(cg * 5 + i) * HC1_];

  int c = isX ? (int)blockIdx.x : (int)blockIdx.x - 16;
  const int cstep = (int)gridDim.x - 16;

  for (;;) {
    const int r0 = c * 64;
    int nr;
    if (isX) nr = 64;                        // 16 blocks x 64 = 1024 ego rows
    else { if (r0 >= total) break; nr = min(64, total - r0); }

    __syncthreads();   // protect rows/rnode from previous iteration readers
    if (tid < 64) rnode[tid] = (tid < nr) ? (isX ? (r0 + tid) * NG_ : meta_node[r0 + tid]) : 0;
    __syncthreads();
    for (int i = tid; i < 64 * 50; i += 512) {
      const int r = i / 50, o8 = i - r * 50;
      if (r < nr)
        *(ushort8v*)&rows[r * S1_ + o8 * 8] =
            *(const ushort8v*)&hg[(size_t)rnode[r] * SG_ + o8 * 8];
    }
    __syncthreads();

    float acc[4][5] = {};
#pragma unroll 2
    for (int ko = 0; ko < 50; ++ko) {
      const int k = ko * 8;
      ushort8v rv[4];
#pragma unroll
      for (int t = 0; t < 4; ++t)
        rv[t] = *(const ushort8v*)&rows[(es + 16 * t) * S1_ + k];
#pragma unroll
      for (int i = 0; i < 5; ++i) {
        const float4 wa = *(const float4*)(wp[i] + k);
        const float4 wb = *(const float4*)(wp[i] + k + 4);
#pragma unroll
        for (int t = 0; t < 4; ++t)
          acc[t][i] = dot8(rv[t], wa, wb, acc[t][i]);
      }
    }

#pragma unroll
    for (int t = 0; t < 4; ++t) {
      const int r = es + 16 * t;
      if (r < nr) {
        float* op = outB + (size_t)(r0 + r) * C2_ + cg * 5;
#pragma unroll
        for (int i = 0; i < 5; ++i) op[i] = acc[t][i] + bias[cg * 5 + i];
      }
    }
    if (isX) break;
    c += cstep;
  }
}

// ---------------------------------------------------------------------------
// K3b: per-graph finisher. One wave per graph, barrier-free: scores (8 lanes
// per edge), two-pass softmax, accumulate, relu -> egoH.
// ---------------------------------------------------------------------------
__global__ __launch_bounds__(64, 4)
void k3b_finish(const float* __restrict__ eattr,
                const float* __restrict__ We2, const float* __restrict__ att2,
                const float* __restrict__ bc2,
                const int* __restrict__ egoOff, const int* __restrict__ meta_eid,
                const float* __restrict__ msgP, const float* __restrict__ xr2v_g,
                float* __restrict__ egoH)
{
  __shared__ float xr2s[C2_];
  __shared__ float scq[EG_], wq[EG_];
  const int b = blockIdx.x, ln = threadIdx.x;
  const int off = egoOff[b];
  const int nE  = egoOff[b + 1] - off;

  if (ln < 40) *(float4*)&xr2s[ln * 4] = *(const float4*)&xr2v_g[(size_t)b * C2_ + ln * 4];

  const int s = ln >> 3, q8 = ln & 7;
  for (int base = 0; base < nE; base += 8) {
    const int j = base + s;
    float sv = 0.f;
    if (j < nE) {
      const int eid = meta_eid[off + j];
      const float* ap = &eattr[(size_t)eid * ED_];
      const float f0 = ap[0], f1 = ap[1], f2 = ap[2];
      const float f3 = ap[3], f4 = ap[4], f5 = ap[5];
      const float* mrow = &msgP[(size_t)(off + j) * C2_];
      for (int i = 0; i < 20; ++i) {
        const int c2 = q8 * 20 + i;
        const float* wv6 = &We2[c2 * ED_];
        float t0 = fmaf(wv6[1], f1, wv6[0] * f0);
        float t1 = fmaf(wv6[3], f3, wv6[2] * f2);
        float t2 = fmaf(wv6[5], f5, wv6[4] * f4);
        float pp = mrow[c2] + xr2s[c2] + (t0 + (t1 + t2));
        pp = fmaxf(pp, 0.2f * pp);
        sv = fmaf(pp, att2[c2], sv);
      }
    }
    sv += __shfl_xor(sv, 1); sv += __shfl_xor(sv, 2); sv += __shfl_xor(sv, 4);
    if (q8 == 0 && j < nE) scq[j] = sv;
  }

  float m = -INFINITY;
  for (int j = ln; j < nE; j += 64) m = fmaxf(m, scq[j]);
#pragma unroll
  for (int d = 1; d < 64; d <<= 1) m = fmaxf(m, __shfl_xor(m, d));

  float den = 0.f;
  for (int j = ln; j < nE; j += 64) {
    const float w = expf(scq[j] - m);
    wq[j] = w;
    den += w;
  }
#pragma unroll
  for (int d = 1; d < 64; d <<= 1) den += __shfl_xor(den, d);
  const float inv = 1.f / (den + 1e-16f);

  float o0 = 0.f, o1 = 0.f, o2 = 0.f;
  for (int j = 0; j < nE; ++j) {
    const float w = wq[j];
    const float* mrow = &msgP[(size_t)(off + j) * C2_];
    o0 = fmaf(w, mrow[ln], o0);
    o1 = fmaf(w, mrow[ln + 64], o1);
    if (ln + 128 < C2_) o2 = fmaf(w, mrow[ln + 128], o2);
  }
  egoH[(size_t)b * C2_ + ln]      = fmaxf(fmaf(o0, inv, bc2[ln]), 0.f);
  egoH[(size_t)b * C2_ + ln + 64] = fmaxf(fmaf(o1, inv, bc2[ln + 64]), 0.f);
  if (ln + 128 < C2_)
    egoH[(size_t)b * C2_ + ln + 128] = fmaxf(fmaf(o2, inv, bc2[ln + 128]), 0.f);
}

// ---------------------------------------------------------------------------
// K4: dense head + MLP (unchanged). 256 blocks x 512 threads.
// ---------------------------------------------------------------------------
__global__ __launch_bounds__(512, 2)
void mlp_head_kernel(
    const float* __restrict__ egoH,
    const float* __restrict__ Wd1, const float* __restrict__ bd1,
    const float* __restrict__ Wd2, const float* __restrict__ bd2,
    const float* __restrict__ Wf1, const float* __restrict__ bf1,
    const float* __restrict__ Wf2, const float* __restrict__ bf2,
    const float* __restrict__ Wm,  const float* __restrict__ bm,
    const float* __restrict__ Ws,  const float* __restrict__ bs,
    float* __restrict__ out)
{
  __shared__ float hE[4 * C2_];
  __shared__ float t1[4 * NG_];
  __shared__ float dbuf[4 * OBS_];
  __shared__ float f1b[4 * 256];
  __shared__ float f2b[4 * 256];

  const int g0  = blockIdx.x * 4;
  const int tid = threadIdx.x;

  for (int i = tid; i < 4 * C2_; i += 512) hE[i] = egoH[g0 * C2_ + i];
  __syncthreads();

  if (tid < 4 * NG_) {
    const int g = tid >> 5, o = tid & 31;
    float acc = bd1[o];
    const float* w  = &Wd1[o * C2_];
    const float* hp = &hE[g * C2_];
    for (int k = 0; k < C2_; k += 4) {
      float4 hv = *(const float4*)(hp + k);
      float4 wv = *(const float4*)(w + k);
      acc = fmaf(hv.x, wv.x, acc); acc = fmaf(hv.y, wv.y, acc);
      acc = fmaf(hv.z, wv.z, acc); acc = fmaf(hv.w, wv.w, acc);
    }
    t1[tid] = acc;
  }
  __syncthreads();

  for (int idx = tid; idx < 4 * OBS_; idx += 512) {
    const int g = idx >> 9, o = idx & 511;
    float acc = bd2[o];
    const float* w  = &Wd2[o * NG_];
    const float* tp = &t1[g * NG_];
#pragma unroll
    for (int k = 0; k < NG_; k += 4) {
      float4 tv = *(const float4*)(tp + k);
      float4 wv = *(const float4*)(w + k);
      acc = fmaf(tv.x, wv.x, acc); acc = fmaf(tv.y, wv.y, acc);
      acc = fmaf(tv.z, wv.z, acc); acc = fmaf(tv.w, wv.w, acc);
    }
    dbuf[idx] = tanhf(acc);
  }
  __syncthreads();

  {
    const int o = tid & 255, gg = tid >> 8;
    const float* w  = &Wf1[o * OBS_];
    const float* dA = &dbuf[(gg * 2 + 0) * OBS_];
    const float* dB = &dbuf[(gg * 2 + 1) * OBS_];
    float a0 = bf1[o], a1 = a0;
#pragma unroll 2
    for (int k = 0; k < OBS_; k += 4) {
      float4 wv = *(const float4*)(w + k);
      float4 xA = *(const float4*)(dA + k);
      float4 xB = *(const float4*)(dB + k);
      a0 = fmaf(xA.x, wv.x, a0); a0 = fmaf(xA.y, wv.y, a0);
      a0 = fmaf(xA.z, wv.z, a0); a0 = fmaf(xA.w, wv.w, a0);
      a1 = fmaf(xB.x, wv.x, a1); a1 = fmaf(xB.y, wv.y, a1);
      a1 = fmaf(xB.z, wv.z, a1); a1 = fmaf(xB.w, wv.w, a1);
    }
    f1b[(gg * 2 + 0) * 256 + o] = fmaxf(a0, 0.f);
    f1b[(gg * 2 + 1) * 256 + o] = fmaxf(a1, 0.f);
  }
  __syncthreads();

  {
    const int o = tid & 255, gg = tid >> 8;
    const float* w  = &Wf2[o * 256];
    const float* dA = &f1b[(gg * 2 + 0) * 256];
    const float* dB = &f1b[(gg * 2 + 1) * 256];
    float a0 = bf2[o], a1 = a0;
#pragma unroll 2
    for (int k = 0; k < 256; k += 4) {
      float4 wv = *(const float4*)(w + k);
      float4 xA = *(const float4*)(dA + k);
      float4 xB = *(const float4*)(dB + k);
      a0 = fmaf(xA.x, wv.x, a0); a0 = fmaf(xA.y, wv.y, a0);
      a0 = fmaf(xA.z, wv.z, a0); a0 = fmaf(xA.w, wv.w, a0);
      a1 = fmaf(xB.x, wv.x, a1); a1 = fmaf(xB.y, wv.y, a1);
      a1 = fmaf(xB.z, wv.z, a1); a1 = fmaf(xB.w, wv.w, a1);
    }
    f2b[(gg * 2 + 0) * 256 + o] = fmaxf(a0, 0.f);
    f2b[(gg * 2 + 1) * 256 + o] = fmaxf(a1, 0.f);
  }
  __syncthreads();

  if (tid < 16) {
    const int g  = tid >> 2;
    const int a  = (tid >> 1) & 1;
    const int hm = tid & 1;
    const float* fp = &f2b[g * 256];
    const float* w  = hm ? &Ws[a * 256] : &Wm[a * 256];
    float acc = hm ? bs[a] : bm[a];
    for (int k = 0; k < 256; ++k) acc = fmaf(fp[k], w[k], acc);
    if (hm == 0) out[(g0 + g) * 2 + a] = acc;
    else         out[2048 + (g0 + g) * 2 + a] = -5.0f + 3.5f * (tanhf(acc) + 1.0f);
  }
}

extern "C" void kernel_launch(void* const* d_in, const int* in_sizes, int n_in,
                              void* d_out, int out_size, void* d_ws, size_t ws_size,
                              hipStream_t stream) {
  const float* x     = (const float*)d_in[0];
  const int*   eidx  = (const int*)d_in[1];
  const float* eattr = (const float*)d_in[2];
  const float* Wl1 = (const float*)d_in[3];  const float* bl1 = (const float*)d_in[4];
  const float* Wr1 = (const float*)d_in[5];  const float* br1 = (const float*)d_in[6];
  const float* We1 = (const float*)d_in[7];  const float* att1= (const float*)d_in[8];
  const float* bc1 = (const float*)d_in[9];
  const float* Wl2 = (const float*)d_in[10]; const float* bl2 = (const float*)d_in[11];
  const float* Wr2 = (const float*)d_in[12]; const float* br2 = (const float*)d_in[13];
  const float* We2 = (const float*)d_in[14]; const float* att2= (const float*)d_in[15];
  const float* bc2 = (const float*)d_in[16];
  const float* Wd1 = (const float*)d_in[17]; const float* bd1 = (const float*)d_in[18];
  const float* Wd2 = (const float*)d_in[19]; const float* bd2 = (const float*)d_in[20];
  const float* Wf1 = (const float*)d_in[21]; const float* bf1 = (const float*)d_in[22];
  const float* Wf2 = (const float*)d_in[23]; const float* bf2 = (const float*)d_in[24];
  const float* Wm  = (const float*)d_in[25]; const float* bm  = (const float*)d_in[26];
  const float* Ws  = (const float*)d_in[27]; const float* bs  = (const float*)d_in[28];

  // workspace layout (~55.5 MB). msgP aliases xlg (dead after K2).
  unsigned short* xlg = (unsigned short*)d_ws;          // [32768][400] bf16 = 26.2 MB
  unsigned short* hg  = xlg + 32768 * SG_;              // xr, then h     = 26.2 MB
  int* eorder_g = (int*)(hg + 32768 * SG_);             // 1.05 MB
  int* bstart_g = eorder_g + ET_;                       // 132 KB
  float* egoH   = (float*)(bstart_g + B_ * 33);         // 640 KB
  int* egoOff   = (int*)(egoH + B_ * C2_);              // 4.1 KB
  int* meta_node= egoOff + (B_ + 1);                    // 160 KB
  int* meta_eid = meta_node + CAP_;                     // 160 KB
  float* xr2v_g = (float*)(meta_eid + CAP_);            // 640 KB
  float* msgP   = (float*)xlg;                          // alias (<= 25 MB used)

  k1_transform_bucket<<<B_, 512, 0, stream>>>(
      x, eidx, Wl1, bl1, Wr1, br1, xlg, hg, eorder_g, bstart_g);

  k0b_pack<<<1, 1024, 0, stream>>>(
      bstart_g, eorder_g, eidx, egoOff, meta_node, meta_eid);

  k2_scores_aggregate<<<B_, 512, 0, stream>>>(
      xlg, hg, eidx, eattr, We1, att1, bc1, eorder_g, bstart_g, hg);

  k3a_gemm<<<160, 512, 0, stream>>>(
      hg, meta_node, egoOff, Wl2, bl2, Wr2, br2, msgP, xr2v_g);

  k3b_finish<<<B_, 64, 0, stream>>>(
      eattr, We2, att2, bc2, egoOff, meta_eid, msgP, xr2v_g, egoH);

  mlp_head_kernel<<<B_ / 4, 512, 0, stream>>>(
      egoH, Wd1, bd1, Wd2, bd2, Wf1, bf1, Wf2, bf2, Wm, bm, Ws, bs,
      (float*)d_out);
}

// Round 10
// 252.891 us; speedup vs baseline: 2.4200x; 1.2628x over previous
//
#include <hip/hip_runtime.h>

#define B_    1024
#define NG_   32
#define F_    16
#define ED_   6
#define EG_   256
#define ET_   262144
#define H1_   5
#define C1_   80
#define HC1_  400
#define C2_   160
#define OBS_  512

#define S1_   408   // LDS bf16 row stride (816B: 16B-aligned, 2-way-max bank alias)
#define SG_   400   // global bf16 row stride
#define CAP_  40960 // packed ego-edge capacity (mean total ~8192)

typedef unsigned short ushort8v __attribute__((ext_vector_type(8)));

__device__ __forceinline__ float bf2f(unsigned short u) {
  return __uint_as_float(((unsigned int)u) << 16);
}
__device__ __forceinline__ unsigned short f2bf(float f) {
  unsigned int u = __float_as_uint(f);
  u = u + 0x7FFFu + ((u >> 16) & 1u);   // RNE
  return (unsigned short)(u >> 16);
}
__device__ __forceinline__ float dot8(ushort8v hv, float4 wa, float4 wb, float acc) {
  acc = fmaf(bf2f(hv[0]), wa.x, acc);
  acc = fmaf(bf2f(hv[1]), wa.y, acc);
  acc = fmaf(bf2f(hv[2]), wa.z, acc);
  acc = fmaf(bf2f(hv[3]), wa.w, acc);
  acc = fmaf(bf2f(hv[4]), wb.x, acc);
  acc = fmaf(bf2f(hv[5]), wb.y, acc);
  acc = fmaf(bf2f(hv[6]), wb.z, acc);
  acc = fmaf(bf2f(hv[7]), wb.w, acc);
  return acc;
}

// ---------------------------------------------------------------------------
// K1: node transforms (waves 0-6, into LDS) + bucket build (wave 7), then one
// coalesced LDS->global copy (16B/lane). r9's direct 2B global column-writes
// caused 218 MB WRITE + 146 MB RMW-FETCH; LDS staging restores full-line
// stores.
// ---------------------------------------------------------------------------
__global__ __launch_bounds__(512, 2)
void k1_transform_bucket(
    const float* __restrict__ x, const int* __restrict__ eidx,
    const float* __restrict__ Wl1, const float* __restrict__ bl1,
    const float* __restrict__ Wr1, const float* __restrict__ br1,
    unsigned short* __restrict__ xlg, unsigned short* __restrict__ xrg,
    int* __restrict__ eorder_g, int* __restrict__ bstart_g)
{
  __shared__ __align__(16) unsigned short xlL[NG_ * S1_];
  __shared__ __align__(16) unsigned short xrL[NG_ * S1_];
  __shared__ float xloc[NG_ * F_];
  __shared__ int   edst[EG_];
  const int b = blockIdx.x, tid = threadIdx.x;
  const int n0 = b * NG_, eb = b * EG_;

  if (tid < EG_) edst[tid] = eidx[ET_ + eb + tid] - n0;
  xloc[tid] = x[n0 * F_ + tid];            // NG_*F_ == 512 == blockDim
  __syncthreads();

  if (tid < 448) {
    // c-major into LDS: thread owns channel(s); 2B LDS stores (2-way alias, free)
    for (int t = 0; t < 2; ++t) {
      const int ch = tid + t * 448;
      if (ch >= 800) break;
      const bool isL = (ch < 400);
      const int  c   = isL ? ch : ch - 400;
      const float* Wp = (isL ? Wl1 : Wr1) + c * F_;
      const float bias = isL ? bl1[c] : br1[c];
      unsigned short* dst = (isL ? xlL : xrL) + c;
      float w[16];
#pragma unroll
      for (int qk = 0; qk < 4; ++qk) {
        float4 v = *(const float4*)(Wp + qk * 4);
        w[qk*4+0] = v.x; w[qk*4+1] = v.y; w[qk*4+2] = v.z; w[qk*4+3] = v.w;
      }
      for (int n = 0; n < NG_; n += 2) {
        const float* xa = &xloc[n * F_];
        float accA = bias, accB = bias;
#pragma unroll
        for (int qk = 0; qk < 4; ++qk) {
          float4 a  = *(const float4*)(xa + qk * 4);
          float4 bv = *(const float4*)(xa + F_ + qk * 4);
          accA = fmaf(a.x,  w[qk*4+0], accA); accA = fmaf(a.y,  w[qk*4+1], accA);
          accA = fmaf(a.z,  w[qk*4+2], accA); accA = fmaf(a.w,  w[qk*4+3], accA);
          accB = fmaf(bv.x, w[qk*4+0], accB); accB = fmaf(bv.y, w[qk*4+1], accB);
          accB = fmaf(bv.z, w[qk*4+2], accB); accB = fmaf(bv.w, w[qk*4+3], accB);
        }
        dst[n * S1_]       = f2bf(accA);
        dst[(n + 1) * S1_] = f2bf(accB);
      }
    }
  } else {
    const int lane = tid & 63;
    const int d    = lane & 31;
    const int half = lane >> 5;
    int cnt = 0;
    const int4* ed4 = (const int4*)edst;
    for (int i = 0; i < 32; ++i) {
      int4 v = ed4[half * 32 + i];
      cnt += (v.x == d) + (v.y == d) + (v.z == d) + (v.w == d);
    }
    const int cnt_lo = __shfl(cnt, d);
    const int total  = cnt + __shfl_xor(cnt, 32);
    int pre = total;
#pragma unroll
    for (int off = 1; off < 32; off <<= 1) {
      int tt = __shfl(pre, lane - off);
      if (d >= off) pre += tt;
    }
    const int start = pre - total;
    if (lane < 32) {
      bstart_g[b * 33 + d] = start;
      if (d == 31) bstart_g[b * 33 + 32] = pre;
    }
    int p = start + (half ? cnt_lo : 0);
    for (int i = 0; i < 32; ++i) {
      int4 v = ed4[half * 32 + i];
      const int e = half * 128 + i * 4;
      if (v.x == d) eorder_g[eb + p++] = e;
      if (v.y == d) eorder_g[eb + p++] = e + 1;
      if (v.z == d) eorder_g[eb + p++] = e + 2;
      if (v.w == d) eorder_g[eb + p++] = e + 3;
    }
  }
  __syncthreads();

  // coalesced LDS -> global (16B/lane, full cache lines)
  for (int i = tid; i < 3200; i += 512) {
    const bool isR = (i >= 1600);
    const int idx = isR ? i - 1600 : i;
    const int n = idx / 50, c8 = idx - n * 50;
    const ushort8v v = *(const ushort8v*)&(isR ? xrL : xlL)[n * S1_ + c8 * 8];
    *(ushort8v*)&(isR ? xrg : xlg)[(n0 + n) * SG_ + c8 * 8] = v;
  }
}

// ---------------------------------------------------------------------------
// K0b: scan nE over graphs -> egoOff; emit packed meta (src node, edge id).
// ---------------------------------------------------------------------------
__global__ __launch_bounds__(1024, 1)
void k0b_pack(const int* __restrict__ bstart_g, const int* __restrict__ eorder_g,
              const int* __restrict__ eidx,
              int* __restrict__ egoOff, int* __restrict__ meta_node,
              int* __restrict__ meta_eid)
{
  __shared__ int scanBuf[B_];
  const int b = threadIdx.x;
  const int nE = bstart_g[b * 33 + 1];
  scanBuf[b] = nE;
  __syncthreads();
  for (int off = 1; off < B_; off <<= 1) {
    int v = (b >= off) ? scanBuf[b - off] : 0;
    __syncthreads();
    scanBuf[b] += v;
    __syncthreads();
  }
  const int start = scanBuf[b] - nE;
  egoOff[b] = start;
  if (b == B_ - 1) egoOff[B_] = scanBuf[b];
  if (start + nE <= CAP_) {
    for (int j = 0; j < nE; ++j) {
      const int e = eorder_g[b * EG_ + j];
      meta_node[start + j] = eidx[b * EG_ + e];   // global src node id
      meta_eid[start + j]  = b * EG_ + e;         // global edge id
    }
  }
}

// ---------------------------------------------------------------------------
// K2: edge scores + segment softmax + aggregation. One block/graph.
// ---------------------------------------------------------------------------
__global__ __launch_bounds__(512, 2)
void k2_scores_aggregate(
    const unsigned short* __restrict__ xlg, const unsigned short* __restrict__ xrg,
    const int* __restrict__ eidx, const float* __restrict__ eattr,
    const float* __restrict__ We1, const float* __restrict__ att1,
    const float* __restrict__ bc1,
    const int* __restrict__ eorder_g, const int* __restrict__ bstart_g,
    unsigned short* __restrict__ hg)
{
  __shared__ __align__(16) unsigned short xl[NG_ * S1_];
  __shared__ __align__(16) unsigned short xr[NG_ * S1_];
  __shared__ float sc0[EG_ * H1_];
  __shared__ float sc1[EG_ * H1_];
  __shared__ float ea[EG_ * ED_];
  __shared__ int   esrc[EG_], edst[EG_], eorder[EG_];
  __shared__ int   bstart[NG_ + 1];
  __shared__ float deninv[NG_ * H1_];

  const int b = blockIdx.x, tid = threadIdx.x;
  const int n0 = b * NG_, eb = b * EG_;

  for (int i = tid; i < 3200; i += 512) {
    const bool isR = (i >= 1600);
    const int idx = isR ? i - 1600 : i;
    const int n = idx / 50, c8 = idx - n * 50;
    const ushort8v v = *(const ushort8v*)&(isR ? xrg : xlg)[(n0 + n) * SG_ + c8 * 8];
    *(ushort8v*)&(isR ? xr : xl)[n * S1_ + c8 * 8] = v;
  }
  if (tid < EG_) {
    esrc[tid]   = eidx[eb + tid] - n0;
    edst[tid]   = eidx[ET_ + eb + tid] - n0;
    eorder[tid] = eorder_g[eb + tid];
  }
  for (int i = tid; i < EG_ * ED_; i += 512) ea[i] = eattr[eb * ED_ + i];
  if (tid < NG_ + 1) bstart[tid] = bstart_g[b * 33 + tid];
  __syncthreads();

  {
    const int e = tid & 255;
    const int s = __builtin_amdgcn_readfirstlane((int)(tid >> 8) & 1);
    float* const scp = s ? sc1 : sc0;
    const int sl = esrc[e], dl = edst[e];
    const float e0 = ea[e*ED_+0], e1 = ea[e*ED_+1], e2 = ea[e*ED_+2];
    const float e3 = ea[e*ED_+3], e4 = ea[e*ED_+4], e5 = ea[e*ED_+5];
    const unsigned short* xlrow = &xl[sl * S1_ + s * 40];
    const unsigned short* xrrow = &xr[dl * S1_ + s * 40];
#pragma unroll
    for (int h = 0; h < H1_; ++h) {
      float sh = 0.f;
#pragma unroll
      for (int co = 0; co < 5; ++co) {
        const int coff  = h * C1_ + co * 8;
        const int cbase = coff + s * 40;
        ushort8v av = *(const ushort8v*)(xlrow + coff);
        ushort8v rv = *(const ushort8v*)(xrrow + coff);
#pragma unroll
        for (int u = 0; u < 8; ++u) {
          const float* wv6 = &We1[(cbase + u) * ED_];
          float t0 = fmaf(wv6[1], e1, wv6[0] * e0);
          float t1 = fmaf(wv6[3], e3, wv6[2] * e2);
          float t2 = fmaf(wv6[5], e5, wv6[4] * e4);
          float p = (bf2f(av[u]) + bf2f(rv[u])) + (t0 + (t1 + t2));
          p = fmaxf(p, 0.2f * p);
          sh = fmaf(p, att1[cbase + u], sh);
        }
      }
      scp[e * H1_ + h] = sh;
    }
  }
  __syncthreads();

  if (tid < NG_ * H1_) {
    const int d = tid & 31, h = tid >> 5;
    const int s0 = bstart[d], s1 = bstart[d + 1];
    float m = -INFINITY;
    for (int k = s0; k < s1; ++k) {
      const int e5i = eorder[k] * H1_ + h;
      m = fmaxf(m, sc0[e5i] + sc1[e5i]);
    }
    float den = 0.f;
    for (int k = s0; k < s1; ++k) {
      const int e5i = eorder[k] * H1_ + h;
      float t = expf(sc0[e5i] + sc1[e5i] - m);
      den += t;
      sc0[e5i] = t;
    }
    deninv[tid] = 1.f / (den + 1e-16f);
  }
  __syncthreads();

  for (int idx = tid; idx < NG_ * 50; idx += 512) {
    const int d  = idx / 50;
    const int co = idx - d * 50;
    const int c  = co * 8;
    const int h  = co / 10;
    const int s0 = bstart[d], s1 = bstart[d + 1];
    float acc[8] = {0.f,0.f,0.f,0.f,0.f,0.f,0.f,0.f};
    for (int k = s0; k < s1; ++k) {
      const int e = eorder[k];
      const float al = sc0[e * H1_ + h];
      ushort8v xv = *(const ushort8v*)(&xl[esrc[e] * S1_ + c]);
#pragma unroll
      for (int u = 0; u < 8; ++u) acc[u] = fmaf(al, bf2f(xv[u]), acc[u]);
    }
    const float inv = deninv[h * 32 + d];
    ushort8v hv;
#pragma unroll
    for (int u = 0; u < 8; ++u)
      hv[u] = f2bf(fmaxf(fmaf(acc[u], inv, bc1[c + u]), 0.f));
    *(ushort8v*)&hg[(n0 + d) * SG_ + c] = hv;
  }
}

// ---------------------------------------------------------------------------
// K3a: packed GEMM. Blocks 0..15: xr2v = ego rows @ Wr2^T (+br2). Blocks
// 16..: grid-stride over packed ego-edge rows, msg = rows @ Wl2^T (+bl2).
// ---------------------------------------------------------------------------
__global__ __launch_bounds__(512, 2)
void k3a_gemm(const unsigned short* __restrict__ hg,
              const int* __restrict__ meta_node, const int* __restrict__ egoOff,
              const float* __restrict__ Wl2, const float* __restrict__ bl2,
              const float* __restrict__ Wr2, const float* __restrict__ br2,
              float* __restrict__ msgP, float* __restrict__ xr2v_g)
{
  __shared__ __align__(16) unsigned short rows[64 * S1_];
  __shared__ int rnode[64];
  __shared__ int sTot;
  const int tid = threadIdx.x;
  const bool isX = (blockIdx.x < 16);
  if (tid == 0) sTot = egoOff[B_];
  __syncthreads();
  const int total = sTot;

  const float* W    = isX ? Wr2 : Wl2;
  const float* bias = isX ? br2 : bl2;
  float* outB       = isX ? xr2v_g : msgP;

  const int es = tid & 15;      // edge slot (rows es, es+16, es+32, es+48)
  const int cg = tid >> 4;      // cc group -> cc = cg*5 + {0..4}
  const float* wp[5];
#pragma unroll
  for (int i = 0; i < 5; ++i) wp[i] = &W[(size_t)(cg * 5 + i) * HC1_];

  int c = isX ? (int)blockIdx.x : (int)blockIdx.x - 16;
  const int cstep = (int)gridDim.x - 16;

  for (;;) {
    const int r0 = c * 64;
    int nr;
    if (isX) nr = 64;
    else { if (r0 >= total) break; nr = min(64, total - r0); }

    __syncthreads();
    if (tid < 64) rnode[tid] = (tid < nr) ? (isX ? (r0 + tid) * NG_ : meta_node[r0 + tid]) : 0;
    __syncthreads();
    for (int i = tid; i < 64 * 50; i += 512) {
      const int r = i / 50, o8 = i - r * 50;
      if (r < nr)
        *(ushort8v*)&rows[r * S1_ + o8 * 8] =
            *(const ushort8v*)&hg[(size_t)rnode[r] * SG_ + o8 * 8];
    }
    __syncthreads();

    float acc[4][5] = {};
#pragma unroll 2
    for (int ko = 0; ko < 50; ++ko) {
      const int k = ko * 8;
      ushort8v rv[4];
#pragma unroll
      for (int t = 0; t < 4; ++t)
        rv[t] = *(const ushort8v*)&rows[(es + 16 * t) * S1_ + k];
#pragma unroll
      for (int i = 0; i < 5; ++i) {
        const float4 wa = *(const float4*)(wp[i] + k);
        const float4 wb = *(const float4*)(wp[i] + k + 4);
#pragma unroll
        for (int t = 0; t < 4; ++t)
          acc[t][i] = dot8(rv[t], wa, wb, acc[t][i]);
      }
    }

#pragma unroll
    for (int t = 0; t < 4; ++t) {
      const int r = es + 16 * t;
      if (r < nr) {
        float* op = outB + (size_t)(r0 + r) * C2_ + cg * 5;
#pragma unroll
        for (int i = 0; i < 5; ++i) op[i] = acc[t][i] + bias[cg * 5 + i];
      }
    }
    if (isX) break;
    c += cstep;
  }
}

// ---------------------------------------------------------------------------
// K3b: per-graph finisher. One wave per graph, barrier-free.
// ---------------------------------------------------------------------------
__global__ __launch_bounds__(64, 4)
void k3b_finish(const float* __restrict__ eattr,
                const float* __restrict__ We2, const float* __restrict__ att2,
                const float* __restrict__ bc2,
                const int* __restrict__ egoOff, const int* __restrict__ meta_eid,
                const float* __restrict__ msgP, const float* __restrict__ xr2v_g,
                float* __restrict__ egoH)
{
  __shared__ float xr2s[C2_];
  __shared__ float scq[EG_], wq[EG_];
  const int b = blockIdx.x, ln = threadIdx.x;
  const int off = egoOff[b];
  const int nE  = egoOff[b + 1] - off;

  if (ln < 40) *(float4*)&xr2s[ln * 4] = *(const float4*)&xr2v_g[(size_t)b * C2_ + ln * 4];

  const int s = ln >> 3, q8 = ln & 7;
  for (int base = 0; base < nE; base += 8) {
    const int j = base + s;
    float sv = 0.f;
    if (j < nE) {
      const int eid = meta_eid[off + j];
      const float* ap = &eattr[(size_t)eid * ED_];
      const float f0 = ap[0], f1 = ap[1], f2 = ap[2];
      const float f3 = ap[3], f4 = ap[4], f5 = ap[5];
      const float* mrow = &msgP[(size_t)(off + j) * C2_];
      for (int i = 0; i < 20; ++i) {
        const int c2 = q8 * 20 + i;
        const float* wv6 = &We2[c2 * ED_];
        float t0 = fmaf(wv6[1], f1, wv6[0] * f0);
        float t1 = fmaf(wv6[3], f3, wv6[2] * f2);
        float t2 = fmaf(wv6[5], f5, wv6[4] * f4);
        float pp = mrow[c2] + xr2s[c2] + (t0 + (t1 + t2));
        pp = fmaxf(pp, 0.2f * pp);
        sv = fmaf(pp, att2[c2], sv);
      }
    }
    sv += __shfl_xor(sv, 1); sv += __shfl_xor(sv, 2); sv += __shfl_xor(sv, 4);
    if (q8 == 0 && j < nE) scq[j] = sv;
  }

  float m = -INFINITY;
  for (int j = ln; j < nE; j += 64) m = fmaxf(m, scq[j]);
#pragma unroll
  for (int d = 1; d < 64; d <<= 1) m = fmaxf(m, __shfl_xor(m, d));

  float den = 0.f;
  for (int j = ln; j < nE; j += 64) {
    const float w = expf(scq[j] - m);
    wq[j] = w;
    den += w;
  }
#pragma unroll
  for (int d = 1; d < 64; d <<= 1) den += __shfl_xor(den, d);
  const float inv = 1.f / (den + 1e-16f);

  float o0 = 0.f, o1 = 0.f, o2 = 0.f;
  for (int j = 0; j < nE; ++j) {
    const float w = wq[j];
    const float* mrow = &msgP[(size_t)(off + j) * C2_];
    o0 = fmaf(w, mrow[ln], o0);
    o1 = fmaf(w, mrow[ln + 64], o1);
    if (ln + 128 < C2_) o2 = fmaf(w, mrow[ln + 128], o2);
  }
  egoH[(size_t)b * C2_ + ln]      = fmaxf(fmaf(o0, inv, bc2[ln]), 0.f);
  egoH[(size_t)b * C2_ + ln + 64] = fmaxf(fmaf(o1, inv, bc2[ln + 64]), 0.f);
  if (ln + 128 < C2_)
    egoH[(size_t)b * C2_ + ln + 128] = fmaxf(fmaf(o2, inv, bc2[ln + 128]), 0.f);
}

// ---------------------------------------------------------------------------
// K4: dense head + MLP (unchanged). 256 blocks x 512 threads.
// ---------------------------------------------------------------------------
__global__ __launch_bounds__(512, 2)
void mlp_head_kernel(
    const float* __restrict__ egoH,
    const float* __restrict__ Wd1, const float* __restrict__ bd1,
    const float* __restrict__ Wd2, const float* __restrict__ bd2,
    const float* __restrict__ Wf1, const float* __restrict__ bf1,
    const float* __restrict__ Wf2, const float* __restrict__ bf2,
    const float* __restrict__ Wm,  const float* __restrict__ bm,
    const float* __restrict__ Ws,  const float* __restrict__ bs,
    float* __restrict__ out)
{
  __shared__ float hE[4 * C2_];
  __shared__ float t1[4 * NG_];
  __shared__ float dbuf[4 * OBS_];
  __shared__ float f1b[4 * 256];
  __shared__ float f2b[4 * 256];

  const int g0  = blockIdx.x * 4;
  const int tid = threadIdx.x;

  for (int i = tid; i < 4 * C2_; i += 512) hE[i] = egoH[g0 * C2_ + i];
  __syncthreads();

  if (tid < 4 * NG_) {
    const int g = tid >> 5, o = tid & 31;
    float acc = bd1[o];
    const float* w  = &Wd1[o * C2_];
    const float* hp = &hE[g * C2_];
    for (int k = 0; k < C2_; k += 4) {
      float4 hv = *(const float4*)(hp + k);
      float4 wv = *(const float4*)(w + k);
      acc = fmaf(hv.x, wv.x, acc); acc = fmaf(hv.y, wv.y, acc);
      acc = fmaf(hv.z, wv.z, acc); acc = fmaf(hv.w, wv.w, acc);
    }
    t1[tid] = acc;
  }
  __syncthreads();

  for (int idx = tid; idx < 4 * OBS_; idx += 512) {
    const int g = idx >> 9, o = idx & 511;
    float acc = bd2[o];
    const float* w  = &Wd2[o * NG_];
    const float* tp = &t1[g * NG_];
#pragma unroll
    for (int k = 0; k < NG_; k += 4) {
      float4 tv = *(const float4*)(tp + k);
      float4 wv = *(const float4*)(w + k);
      acc = fmaf(tv.x, wv.x, acc); acc = fmaf(tv.y, wv.y, acc);
      acc = fmaf(tv.z, wv.z, acc); acc = fmaf(tv.w, wv.w, acc);
    }
    dbuf[idx] = tanhf(acc);
  }
  __syncthreads();

  {
    const int o = tid & 255, gg = tid >> 8;
    const float* w  = &Wf1[o * OBS_];
    const float* dA = &dbuf[(gg * 2 + 0) * OBS_];
    const float* dB = &dbuf[(gg * 2 + 1) * OBS_];
    float a0 = bf1[o], a1 = a0;
#pragma unroll 2
    for (int k = 0; k < OBS_; k += 4) {
      float4 wv = *(const float4*)(w + k);
      float4 xA = *(const float4*)(dA + k);
      float4 xB = *(const float4*)(dB + k);
      a0 = fmaf(xA.x, wv.x, a0); a0 = fmaf(xA.y, wv.y, a0);
      a0 = fmaf(xA.z, wv.z, a0); a0 = fmaf(xA.w, wv.w, a0);
      a1 = fmaf(xB.x, wv.x, a1); a1 = fmaf(xB.y, wv.y, a1);
      a1 = fmaf(xB.z, wv.z, a1); a1 = fmaf(xB.w, wv.w, a1);
    }
    f1b[(gg * 2 + 0) * 256 + o] = fmaxf(a0, 0.f);
    f1b[(gg * 2 + 1) * 256 + o] = fmaxf(a1, 0.f);
  }
  __syncthreads();

  {
    const int o = tid & 255, gg = tid >> 8;
    const float* w  = &Wf2[o * 256];
    const float* dA = &f1b[(gg * 2 + 0) * 256];
    const float* dB = &f1b[(gg * 2 + 1) * 256];
    float a0 = bf2[o], a1 = a0;
#pragma unroll 2
    for (int k = 0; k < 256; k += 4) {
      float4 wv = *(const float4*)(w + k);
      float4 xA = *(const float4*)(dA + k);
      float4 xB = *(const float4*)(dB + k);
      a0 = fmaf(xA.x, wv.x, a0); a0 = fmaf(xA.y, wv.y, a0);
      a0 = fmaf(xA.z, wv.z, a0); a0 = fmaf(xA.w, wv.w, a0);
      a1 = fmaf(xB.x, wv.x, a1); a1 = fmaf(xB.y, wv.y, a1);
      a1 = fmaf(xB.z, wv.z, a1); a1 = fmaf(xB.w, wv.w, a1);
    }
    f2b[(gg * 2 + 0) * 256 + o] = fmaxf(a0, 0.f);
    f2b[(gg * 2 + 1) * 256 + o] = fmaxf(a1, 0.f);
  }
  __syncthreads();

  if (tid < 16) {
    const int g  = tid >> 2;
    const int a  = (tid >> 1) & 1;
    const int hm = tid & 1;
    const float* fp = &f2b[g * 256];
    const float* w  = hm ? &Ws[a * 256] : &Wm[a * 256];
    float acc = hm ? bs[a] : bm[a];
    for (int k = 0; k < 256; ++k) acc = fmaf(fp[k], w[k], acc);
    if (hm == 0) out[(g0 + g) * 2 + a] = acc;
    else         out[2048 + (g0 + g) * 2 + a] = -5.0f + 3.5f * (tanhf(acc) + 1.0f);
  }
}

extern "C" void kernel_launch(void* const* d_in, const int* in_sizes, int n_in,
                              void* d_out, int out_size, void* d_ws, size_t ws_size,
                              hipStream_t stream) {
  const float* x     = (const float*)d_in[0];
  const int*   eidx  = (const int*)d_in[1];
  const float* eattr = (const float*)d_in[2];
  const float* Wl1 = (const float*)d_in[3];  const float* bl1 = (const float*)d_in[4];
  const float* Wr1 = (const float*)d_in[5];  const float* br1 = (const float*)d_in[6];
  const float* We1 = (const float*)d_in[7];  const float* att1= (const float*)d_in[8];
  const float* bc1 = (const float*)d_in[9];
  const float* Wl2 = (const float*)d_in[10]; const float* bl2 = (const float*)d_in[11];
  const float* Wr2 = (const float*)d_in[12]; const float* br2 = (const float*)d_in[13];
  const float* We2 = (const float*)d_in[14]; const float* att2= (const float*)d_in[15];
  const float* bc2 = (const float*)d_in[16];
  const float* Wd1 = (const float*)d_in[17]; const float* bd1 = (const float*)d_in[18];
  const float* Wd2 = (const float*)d_in[19]; const float* bd2 = (const float*)d_in[20];
  const float* Wf1 = (const float*)d_in[21]; const float* bf1 = (const float*)d_in[22];
  const float* Wf2 = (const float*)d_in[23]; const float* bf2 = (const float*)d_in[24];
  const float* Wm  = (const float*)d_in[25]; const float* bm  = (const float*)d_in[26];
  const float* Ws  = (const float*)d_in[27]; const float* bs  = (const float*)d_in[28];

  // workspace layout (~55.5 MB). msgP aliases xlg (dead after K2).
  unsigned short* xlg = (unsigned short*)d_ws;          // [32768][400] bf16 = 26.2 MB
  unsigned short* hg  = xlg + 32768 * SG_;              // xr, then h     = 26.2 MB
  int* eorder_g = (int*)(hg + 32768 * SG_);             // 1.05 MB
  int* bstart_g = eorder_g + ET_;                       // 132 KB
  float* egoH   = (float*)(bstart_g + B_ * 33);         // 640 KB
  int* egoOff   = (int*)(egoH + B_ * C2_);              // 4.1 KB
  int* meta_node= egoOff + (B_ + 1);                    // 160 KB
  int* meta_eid = meta_node + CAP_;                     // 160 KB
  float* xr2v_g = (float*)(meta_eid + CAP_);            // 640 KB
  float* msgP   = (float*)xlg;                          // alias (<= 25 MB used)

  k1_transform_bucket<<<B_, 512, 0, stream>>>(
      x, eidx, Wl1, bl1, Wr1, br1, xlg, hg, eorder_g, bstart_g);

  k0b_pack<<<1, 1024, 0, stream>>>(
      bstart_g, eorder_g, eidx, egoOff, meta_node, meta_eid);

  k2_scores_aggregate<<<B_, 512, 0, stream>>>(
      xlg, hg, eidx, eattr, We1, att1, bc1, eorder_g, bstart_g, hg);

  k3a_gemm<<<160, 512, 0, stream>>>(
      hg, meta_node, egoOff, Wl2, bl2, Wr2, br2, msgP, xr2v_g);

  k3b_finish<<<B_, 64, 0, stream>>>(
      eattr, We2, att2, bc2, egoOff, meta_eid, msgP, xr2v_g, egoH);

  mlp_head_kernel<<<B_ / 4, 512, 0, stream>>>(
      egoH, Wd1, bd1, Wd2, bd2, Wf1, bf1, Wf2, bf2, Wm, bm, Ws, bs,
      (float*)d_out);
}